// Round 5
// baseline (227.017 us; speedup 1.0000x reference)
//
#include <hip/hip_runtime.h>
#include <math.h>

#define DIM 512
#define NH 8
#define HD 64
#define SS 2048
#define NB 2

typedef __bf16 bf16;
typedef __attribute__((ext_vector_type(8))) __bf16 bf16x8;
typedef __attribute__((ext_vector_type(4))) __bf16 bf16x4;
typedef __attribute__((ext_vector_type(4))) float f32x4;

// convert 8 consecutive floats -> bf16x8
__device__ inline bf16x8 cvt8(const float* s) {
  bf16x8 o;
#pragma unroll
  for (int i = 0; i < 8; ++i) o[i] = (bf16)s[i];
  return o;
}

// ---------------------------------------------------------------------------
// K1: QKV projection, bf16 MFMA (R3-verified form).
// y = x @ W^T + b -> bf16 head layout [B,H,S,HD]; q pre-scaled by 0.125.
// ---------------------------------------------------------------------------
__global__ __launch_bounds__(256) void qkv_proj_kernel(
    const float* __restrict__ xq, const float* __restrict__ xk, const float* __restrict__ xv,
    const float* __restrict__ Wq, const float* __restrict__ bq,
    const float* __restrict__ Wk, const float* __restrict__ bk,
    const float* __restrict__ Wv, const float* __restrict__ bv,
    bf16* __restrict__ qh, bf16* __restrict__ kh, bf16* __restrict__ vh)
{
  const int which = blockIdx.z;
  const float* A    = (which == 0) ? xq : (which == 1) ? xk : xv;
  const float* W    = (which == 0) ? Wq : (which == 1) ? Wk : Wv;
  const float* bias = (which == 0) ? bq : (which == 1) ? bk : bv;
  bf16* out         = (which == 0) ? qh : (which == 1) ? kh : vh;
  const float oscale = (which == 0) ? 0.125f : 1.0f;

  __shared__ bf16 As[128][72];
  __shared__ bf16 Bs[64][72];

  const int m0 = blockIdx.x * 128;
  const int n0 = blockIdx.y * 64;
  const int tid = threadIdx.x;
  const int w = tid >> 6, l = tid & 63;
  const int l16 = l & 15, lg = l >> 4;
  const int wm = w >> 1, wn = w & 1;

  f32x4 acc[4][2];
#pragma unroll
  for (int mf = 0; mf < 4; ++mf)
#pragma unroll
    for (int nf = 0; nf < 2; ++nf) acc[mf][nf] = (f32x4){0.f, 0.f, 0.f, 0.f};

  for (int k0 = 0; k0 < DIM; k0 += 64) {
    __syncthreads();
    {  // stage A: 128 rows x 64 k
      const int r = tid >> 1, hf = (tid & 1) * 32;
      const float* src = &A[(size_t)(m0 + r) * DIM + k0 + hf];
      bf16* dst = &As[r][hf];
#pragma unroll
      for (int i = 0; i < 4; ++i) ((bf16x8*)dst)[i] = cvt8(src + i * 8);
    }
    if (tid < 128) {  // stage B (W rows): 64 rows x 64 k
      const int r = tid >> 1, hf = (tid & 1) * 32;
      const float* src = &W[(size_t)(n0 + r) * DIM + k0 + hf];
      bf16* dst = &Bs[r][hf];
#pragma unroll
      for (int i = 0; i < 4; ++i) ((bf16x8*)dst)[i] = cvt8(src + i * 8);
    }
    __syncthreads();

#pragma unroll
    for (int kk = 0; kk < 2; ++kk) {
      bf16x8 bfr[2];
      bfr[0] = *(const bf16x8*)&Bs[wn * 32 + l16][kk * 32 + lg * 8];
      bfr[1] = *(const bf16x8*)&Bs[wn * 32 + 16 + l16][kk * 32 + lg * 8];
#pragma unroll
      for (int mf = 0; mf < 4; ++mf) {
        const bf16x8 af = *(const bf16x8*)&As[wm * 64 + mf * 16 + l16][kk * 32 + lg * 8];
        acc[mf][0] = __builtin_amdgcn_mfma_f32_16x16x32_bf16(af, bfr[0], acc[mf][0], 0, 0, 0);
        acc[mf][1] = __builtin_amdgcn_mfma_f32_16x16x32_bf16(af, bfr[1], acc[mf][1], 0, 0, 0);
      }
    }
  }

  const int h = blockIdx.y;
#pragma unroll
  for (int mf = 0; mf < 4; ++mf) {
#pragma unroll
    for (int nf = 0; nf < 2; ++nf) {
      const int d = wn * 32 + nf * 16 + l16;
#pragma unroll
      for (int ri = 0; ri < 4; ++ri) {
        const int row = m0 + wm * 64 + mf * 16 + lg * 4 + ri;
        const int b = row >> 11, s = row & 2047;
        out[((size_t)(b * NH + h) * SS + s) * HD + d] =
            (bf16)((acc[mf][nf][ri] + bias[n0 + d]) * oscale);
      }
    }
  }
}

// ---------------------------------------------------------------------------
// K2: MFMA flash attention, two-pass. K fragments read DIRECT from global
// (L2-resident, 256 KiB/head) -> pass 1 has no barriers, no LDS; pass 2
// stages only Vt (transposed, all 256 threads). LDS 34.8 KiB -> 4 WG/CU.
// ---------------------------------------------------------------------------
__global__ __launch_bounds__(256) void attn_kernel(
    const bf16* __restrict__ qh, const bf16* __restrict__ kh, const bf16* __restrict__ vh,
    float* __restrict__ attn, bf16* __restrict__ ctx)
{
  __shared__ bf16 Vt[64][136];     // V tile transposed [d][t], +8 pad
  __shared__ bf16 Ps[4][16][136];  // per-wave P transpose buffer

  const int bh = blockIdx.y;
  const int q0 = blockIdx.x * 64;
  const int tid = threadIdx.x;
  const int w   = tid >> 6;
  const int l   = tid & 63;
  const int l16 = l & 15;
  const int lg  = l >> 4;

  const bf16* qp = qh + (size_t)bh * SS * HD;
  const bf16* kp = kh + (size_t)bh * SS * HD;
  const bf16* vp = vh + (size_t)bh * SS * HD;

  const int qrow = q0 + w * 16 + l16;
  const bf16x8 qf0 = *(const bf16x8*)&qp[(size_t)qrow * HD + lg * 8];
  const bf16x8 qf1 = *(const bf16x8*)&qp[(size_t)qrow * HD + 32 + lg * 8];

  float m_run[4], l_run[4];
#pragma unroll
  for (int rr = 0; rr < 4; ++rr) { m_run[rr] = -1e30f; l_run[rr] = 0.f; }

  // ---------------- pass 1: row max & sum (no LDS, no barriers) -----------
  for (int t0 = 0; t0 < SS; t0 += 128) {
    f32x4 accS[8];
#pragma unroll
    for (int n = 0; n < 8; ++n) {
      const bf16* krow = &kp[(size_t)(t0 + n * 16 + l16) * HD + lg * 8];
      const bf16x8 kf0 = *(const bf16x8*)krow;
      const bf16x8 kf1 = *(const bf16x8*)(krow + 32);
      f32x4 a = {0.f, 0.f, 0.f, 0.f};
      a = __builtin_amdgcn_mfma_f32_16x16x32_bf16(qf0, kf0, a, 0, 0, 0);
      a = __builtin_amdgcn_mfma_f32_16x16x32_bf16(qf1, kf1, a, 0, 0, 0);
      accS[n] = a;
    }
#pragma unroll
    for (int rr = 0; rr < 4; ++rr) {
      float tmax = accS[0][rr];
#pragma unroll
      for (int n = 1; n < 8; ++n) tmax = fmaxf(tmax, accS[n][rr]);
      const float nm = fmaxf(m_run[rr], tmax);
      float sum = 0.f;
#pragma unroll
      for (int n = 0; n < 8; ++n) sum += __expf(accS[n][rr] - nm);
      l_run[rr] = l_run[rr] * __expf(m_run[rr] - nm) + sum;
      m_run[rr] = nm;
    }
  }

  // reduce (m,l) across the 16 lanes sharing the same 4 rows
#pragma unroll
  for (int rr = 0; rr < 4; ++rr) {
    float m = m_run[rr], ls = l_run[rr];
#pragma unroll
    for (int off = 1; off < 16; off <<= 1) {
      const float m2 = __shfl_xor(m, off);
      const float l2 = __shfl_xor(ls, off);
      const float nm = fmaxf(m, m2);
      ls = ls * __expf(m - nm) + l2 * __expf(m2 - nm);
      m = nm;
    }
    m_run[rr] = m;
    l_run[rr] = 1.f / ls;
  }

  // ---------------- pass 2: P write + P.V ----------------
  f32x4 accC[4];
#pragma unroll
  for (int dt = 0; dt < 4; ++dt) accC[dt] = (f32x4){0.f, 0.f, 0.f, 0.f};

  float* arow_base = attn + ((size_t)(bh * SS + q0 + w * 16)) * SS;

  const int vg  = tid & 31;   // t-group: rows 4*vg..4*vg+3
  const int vdc = tid >> 5;   // d-chunk: 8*vdc..8*vdc+7

  for (int t0 = 0; t0 < SS; t0 += 128) {
    __syncthreads();   // previous tile's Vt reads complete
    {  // stage Vt: each thread 4 t-rows x 8 d, in-register transpose
      bf16x8 vr[4];
#pragma unroll
      for (int i = 0; i < 4; ++i)
        vr[i] = *(const bf16x8*)&vp[(size_t)(t0 + vg * 4 + i) * HD + vdc * 8];
#pragma unroll
      for (int j = 0; j < 8; ++j) {
        bf16x4 o;
#pragma unroll
        for (int i = 0; i < 4; ++i) o[i] = vr[i][j];
        *(bf16x4*)&Vt[vdc * 8 + j][vg * 4] = o;
      }
    }
    __syncthreads();

    f32x4 accS[8];
#pragma unroll
    for (int n = 0; n < 8; ++n) {
      const bf16* krow = &kp[(size_t)(t0 + n * 16 + l16) * HD + lg * 8];
      const bf16x8 kf0 = *(const bf16x8*)krow;
      const bf16x8 kf1 = *(const bf16x8*)(krow + 32);
      f32x4 a = {0.f, 0.f, 0.f, 0.f};
      a = __builtin_amdgcn_mfma_f32_16x16x32_bf16(qf0, kf0, a, 0, 0, 0);
      a = __builtin_amdgcn_mfma_f32_16x16x32_bf16(qf1, kf1, a, 0, 0, 0);
      accS[n] = a;
    }

#pragma unroll
    for (int n = 0; n < 8; ++n) {
#pragma unroll
      for (int rr = 0; rr < 4; ++rr) {
        const int row = lg * 4 + rr;
        const float p = __expf(accS[n][rr] - m_run[rr]) * l_run[rr];
        arow_base[(size_t)row * SS + t0 + n * 16 + l16] = p;
        Ps[w][row][n * 16 + l16] = (bf16)p;
      }
    }

#pragma unroll
    for (int ts = 0; ts < 4; ++ts) {
      const bf16x8 pa = *(const bf16x8*)&Ps[w][l16][ts * 32 + lg * 8];
#pragma unroll
      for (int dt = 0; dt < 4; ++dt) {
        const bf16x8 vb = *(const bf16x8*)&Vt[dt * 16 + l16][ts * 32 + lg * 8];
        accC[dt] = __builtin_amdgcn_mfma_f32_16x16x32_bf16(pa, vb, accC[dt], 0, 0, 0);
      }
    }
  }

  const int b = bh >> 3, h = bh & 7;
#pragma unroll
  for (int dt = 0; dt < 4; ++dt)
#pragma unroll
    for (int rr = 0; rr < 4; ++rr) {
      const int s = q0 + w * 16 + lg * 4 + rr;
      ctx[((size_t)b * SS + s) * DIM + h * HD + dt * 16 + l16] = (bf16)accC[dt][rr];
    }
}

// ---------------------------------------------------------------------------
// K3: output projection, bf16 MFMA (R3-verified form). out = ctx @ Wo^T + bo.
// ---------------------------------------------------------------------------
__global__ __launch_bounds__(256) void out_proj_kernel(
    const bf16* __restrict__ ctx, const float* __restrict__ Wo, const float* __restrict__ bo,
    float* __restrict__ out)
{
  __shared__ bf16 As[128][72];
  __shared__ bf16 Bs[64][72];

  const int m0 = blockIdx.x * 128;
  const int n0 = blockIdx.y * 64;
  const int tid = threadIdx.x;
  const int w = tid >> 6, l = tid & 63;
  const int l16 = l & 15, lg = l >> 4;
  const int wm = w >> 1, wn = w & 1;

  f32x4 acc[4][2];
#pragma unroll
  for (int mf = 0; mf < 4; ++mf)
#pragma unroll
    for (int nf = 0; nf < 2; ++nf) acc[mf][nf] = (f32x4){0.f, 0.f, 0.f, 0.f};

  for (int k0 = 0; k0 < DIM; k0 += 64) {
    __syncthreads();
    {  // stage A (already bf16, contiguous)
      const int r = tid >> 1, hf = (tid & 1) * 32;
      const bf16* src = &ctx[(size_t)(m0 + r) * DIM + k0 + hf];
      bf16* dst = &As[r][hf];
#pragma unroll
      for (int i = 0; i < 4; ++i) ((bf16x8*)dst)[i] = ((const bf16x8*)src)[i];
    }
    if (tid < 128) {
      const int r = tid >> 1, hf = (tid & 1) * 32;
      const float* src = &Wo[(size_t)(n0 + r) * DIM + k0 + hf];
      bf16* dst = &Bs[r][hf];
#pragma unroll
      for (int i = 0; i < 4; ++i) ((bf16x8*)dst)[i] = cvt8(src + i * 8);
    }
    __syncthreads();

#pragma unroll
    for (int kk = 0; kk < 2; ++kk) {
      bf16x8 bfr[2];
      bfr[0] = *(const bf16x8*)&Bs[wn * 32 + l16][kk * 32 + lg * 8];
      bfr[1] = *(const bf16x8*)&Bs[wn * 32 + 16 + l16][kk * 32 + lg * 8];
#pragma unroll
      for (int mf = 0; mf < 4; ++mf) {
        const bf16x8 af = *(const bf16x8*)&As[wm * 64 + mf * 16 + l16][kk * 32 + lg * 8];
        acc[mf][0] = __builtin_amdgcn_mfma_f32_16x16x32_bf16(af, bfr[0], acc[mf][0], 0, 0, 0);
        acc[mf][1] = __builtin_amdgcn_mfma_f32_16x16x32_bf16(af, bfr[1], acc[mf][1], 0, 0, 0);
      }
    }
  }

#pragma unroll
  for (int mf = 0; mf < 4; ++mf) {
#pragma unroll
    for (int nf = 0; nf < 2; ++nf) {
      const int c = n0 + wn * 32 + nf * 16 + l16;
#pragma unroll
      for (int ri = 0; ri < 4; ++ri) {
        const int row = m0 + wm * 64 + mf * 16 + lg * 4 + ri;
        out[(size_t)row * DIM + c] = acc[mf][nf][ri] + bo[c];
      }
    }
  }
}

// ---------------------------------------------------------------------------
extern "C" void kernel_launch(void* const* d_in, const int* in_sizes, int n_in,
                              void* d_out, int out_size, void* d_ws, size_t ws_size,
                              hipStream_t stream) {
  const float* q  = (const float*)d_in[0];
  const float* k  = (const float*)d_in[1];
  const float* v  = (const float*)d_in[2];
  const float* Wq = (const float*)d_in[3];
  const float* bq = (const float*)d_in[4];
  const float* Wk = (const float*)d_in[5];
  const float* bk = (const float*)d_in[6];
  const float* Wv = (const float*)d_in[7];
  const float* bv = (const float*)d_in[8];
  const float* Wo = (const float*)d_in[9];
  const float* bo = (const float*)d_in[10];

  float* out0 = (float*)d_out;                     // [2,2048,512] fp32
  float* attn = out0 + (size_t)NB * SS * DIM;      // [2,8,2048,2048] fp32

  const size_t HSZ = (size_t)NB * NH * SS * HD;
  bf16* qh  = (bf16*)d_ws;
  bf16* kh  = qh + HSZ;
  bf16* vh  = kh + HSZ;
  bf16* ctx = vh + HSZ;                            // bf16 flat [B,S,DIM]

  dim3 g1(NB * SS / 128, DIM / 64, 3);
  qkv_proj_kernel<<<g1, 256, 0, stream>>>(q, k, v, Wq, bq, Wk, bk, Wv, bv, qh, kh, vh);

  dim3 g2(SS / 64, NB * NH);
  attn_kernel<<<g2, 256, 0, stream>>>(qh, kh, vh, attn, ctx);

  dim3 g3(NB * SS / 128, DIM / 64);
  out_proj_kernel<<<g3, 256, 0, stream>>>(ctx, Wo, bo, out0);
}

// Round 6
// 152.097 us; speedup vs baseline: 1.4926x; 1.4926x over previous
//
#include <hip/hip_runtime.h>
#include <math.h>

#define DIM 512
#define NH 8
#define HD 64
#define SS 2048
#define NB 2

typedef __bf16 bf16;
typedef __attribute__((ext_vector_type(8))) __bf16 bf16x8;
typedef __attribute__((ext_vector_type(4))) __bf16 bf16x4;
typedef __attribute__((ext_vector_type(2))) __bf16 bf16x2;
typedef __attribute__((ext_vector_type(4))) float f32x4;

// convert 8 consecutive floats -> bf16x8
__device__ inline bf16x8 cvt8(const float* s) {
  bf16x8 o;
#pragma unroll
  for (int i = 0; i < 8; ++i) o[i] = (bf16)s[i];
  return o;
}

// ---------------------------------------------------------------------------
// K1: QKV projection, bf16 MFMA (R3-verified form).
// y = x @ W^T + b -> bf16 head layout [B,H,S,HD]; q pre-scaled by 0.125.
// ---------------------------------------------------------------------------
__global__ __launch_bounds__(256) void qkv_proj_kernel(
    const float* __restrict__ xq, const float* __restrict__ xk, const float* __restrict__ xv,
    const float* __restrict__ Wq, const float* __restrict__ bq,
    const float* __restrict__ Wk, const float* __restrict__ bk,
    const float* __restrict__ Wv, const float* __restrict__ bv,
    bf16* __restrict__ qh, bf16* __restrict__ kh, bf16* __restrict__ vh)
{
  const int which = blockIdx.z;
  const float* A    = (which == 0) ? xq : (which == 1) ? xk : xv;
  const float* W    = (which == 0) ? Wq : (which == 1) ? Wk : Wv;
  const float* bias = (which == 0) ? bq : (which == 1) ? bk : bv;
  bf16* out         = (which == 0) ? qh : (which == 1) ? kh : vh;
  const float oscale = (which == 0) ? 0.125f : 1.0f;

  __shared__ bf16 As[128][72];
  __shared__ bf16 Bs[64][72];

  const int m0 = blockIdx.x * 128;
  const int n0 = blockIdx.y * 64;
  const int tid = threadIdx.x;
  const int w = tid >> 6, l = tid & 63;
  const int l16 = l & 15, lg = l >> 4;
  const int wm = w >> 1, wn = w & 1;

  f32x4 acc[4][2];
#pragma unroll
  for (int mf = 0; mf < 4; ++mf)
#pragma unroll
    for (int nf = 0; nf < 2; ++nf) acc[mf][nf] = (f32x4){0.f, 0.f, 0.f, 0.f};

  for (int k0 = 0; k0 < DIM; k0 += 64) {
    __syncthreads();
    {
      const int r = tid >> 1, hf = (tid & 1) * 32;
      const float* src = &A[(size_t)(m0 + r) * DIM + k0 + hf];
      bf16* dst = &As[r][hf];
#pragma unroll
      for (int i = 0; i < 4; ++i) ((bf16x8*)dst)[i] = cvt8(src + i * 8);
    }
    if (tid < 128) {
      const int r = tid >> 1, hf = (tid & 1) * 32;
      const float* src = &W[(size_t)(n0 + r) * DIM + k0 + hf];
      bf16* dst = &Bs[r][hf];
#pragma unroll
      for (int i = 0; i < 4; ++i) ((bf16x8*)dst)[i] = cvt8(src + i * 8);
    }
    __syncthreads();

#pragma unroll
    for (int kk = 0; kk < 2; ++kk) {
      bf16x8 bfr[2];
      bfr[0] = *(const bf16x8*)&Bs[wn * 32 + l16][kk * 32 + lg * 8];
      bfr[1] = *(const bf16x8*)&Bs[wn * 32 + 16 + l16][kk * 32 + lg * 8];
#pragma unroll
      for (int mf = 0; mf < 4; ++mf) {
        const bf16x8 af = *(const bf16x8*)&As[wm * 64 + mf * 16 + l16][kk * 32 + lg * 8];
        acc[mf][0] = __builtin_amdgcn_mfma_f32_16x16x32_bf16(af, bfr[0], acc[mf][0], 0, 0, 0);
        acc[mf][1] = __builtin_amdgcn_mfma_f32_16x16x32_bf16(af, bfr[1], acc[mf][1], 0, 0, 0);
      }
    }
  }

  const int h = blockIdx.y;
#pragma unroll
  for (int mf = 0; mf < 4; ++mf) {
#pragma unroll
    for (int nf = 0; nf < 2; ++nf) {
      const int d = wn * 32 + nf * 16 + l16;
#pragma unroll
      for (int ri = 0; ri < 4; ++ri) {
        const int row = m0 + wm * 64 + mf * 16 + lg * 4 + ri;
        const int b = row >> 11, s = row & 2047;
        out[((size_t)(b * NH + h) * SS + s) * HD + d] =
            (bf16)((acc[mf][nf][ri] + bias[n0 + d]) * oscale);
      }
    }
  }
}

// ---------------------------------------------------------------------------
// K2: MFMA flash attention, two-pass. 512 threads = 8 waves:
// wave (wq,wt): wq in 0..3 -> 16 q-rows; wt in 0..1 -> t-half (1024 each).
// 2 WG/CU x 8 waves = 16 waves/CU. K staged in LDS per t-half; Vt staged
// transposed with 8-elem-block XOR swizzle (write 2-way max, read uniform).
// Cross-wt (m,l) merge and ctx 2-way reduce in LDS.
// ---------------------------------------------------------------------------
__global__ __launch_bounds__(512, 4) void attn_kernel(
    const bf16* __restrict__ qh, const bf16* __restrict__ kh, const bf16* __restrict__ vh,
    float* __restrict__ attn, bf16* __restrict__ ctx)
{
  __shared__ bf16 Ks[2][64][72];       // K tile per t-half [t][d]
  __shared__ bf16 Vt[2][64][72];       // V^T tile per t-half [d][t-swizzled]
  __shared__ bf16 Ps[8][16][72];       // per-wave P transpose
  __shared__ float ctxred[4][16][68];  // wt=1 ctx partials
  __shared__ float mlredA[4][16][2];   // wt=1 (m,l) partials
  __shared__ float mlredB[4][16][2];   // final (m, inv_l)

  const int bh = blockIdx.y;
  const int q0 = blockIdx.x * 64;
  const int tid = threadIdx.x;
  const int w   = tid >> 6;     // 0..7
  const int wq  = w >> 1;       // 0..3
  const int wt  = w & 1;        // 0..1
  const int l   = tid & 63;
  const int l16 = l & 15;
  const int lg  = l >> 4;

  const bf16* qp = qh + (size_t)bh * SS * HD;
  const bf16* kp = kh + (size_t)bh * SS * HD;
  const bf16* vp = vh + (size_t)bh * SS * HD;

  // staging maps (512 threads cover both t-half tiles each iteration)
  const int ks_wt = tid >> 8;          // 0..1
  const int ks_r  = (tid >> 2) & 63;   // 0..63
  const int ks_c  = (tid & 3) * 16;    // 0,16,32,48
  const int vs_wt = tid >> 8;
  const int vs_rc = (tid >> 3) & 31;   // 2-row chunk 0..31
  const int vs_dc = tid & 7;           // 8-d chunk 0..7

  const int qrow = q0 + wq * 16 + l16;
  const bf16x8 qf0 = *(const bf16x8*)&qp[(size_t)qrow * HD + lg * 8];
  const bf16x8 qf1 = *(const bf16x8*)&qp[(size_t)qrow * HD + 32 + lg * 8];

  const int tbase = wt * 1024;

  float m_run[4], l_run[4];
#pragma unroll
  for (int rr = 0; rr < 4; ++rr) { m_run[rr] = -1e30f; l_run[rr] = 0.f; }

  // ---------------- pass 1: row max & sum over this wave's t-half ----------
  for (int tt = 0; tt < 1024; tt += 64) {
    __syncthreads();
    {  // stage K tiles (both halves)
      const bf16* src = &kp[(size_t)(ks_wt * 1024 + tt + ks_r) * HD + ks_c];
      bf16* dst = &Ks[ks_wt][ks_r][ks_c];
      ((bf16x8*)dst)[0] = ((const bf16x8*)src)[0];
      ((bf16x8*)dst)[1] = ((const bf16x8*)src)[1];
    }
    __syncthreads();

    f32x4 accS[4];
#pragma unroll
    for (int n = 0; n < 4; ++n) {
      const bf16x8 kf0 = *(const bf16x8*)&Ks[wt][n * 16 + l16][lg * 8];
      const bf16x8 kf1 = *(const bf16x8*)&Ks[wt][n * 16 + l16][32 + lg * 8];
      f32x4 a = {0.f, 0.f, 0.f, 0.f};
      a = __builtin_amdgcn_mfma_f32_16x16x32_bf16(qf0, kf0, a, 0, 0, 0);
      a = __builtin_amdgcn_mfma_f32_16x16x32_bf16(qf1, kf1, a, 0, 0, 0);
      accS[n] = a;
    }
#pragma unroll
    for (int rr = 0; rr < 4; ++rr) {
      float tmax = accS[0][rr];
#pragma unroll
      for (int n = 1; n < 4; ++n) tmax = fmaxf(tmax, accS[n][rr]);
      const float nm = fmaxf(m_run[rr], tmax);
      float sum = 0.f;
#pragma unroll
      for (int n = 0; n < 4; ++n) sum += __expf(accS[n][rr] - nm);
      l_run[rr] = l_run[rr] * __expf(m_run[rr] - nm) + sum;
      m_run[rr] = nm;
    }
  }

  // reduce (m,l) across the 16 lanes sharing the same rows
#pragma unroll
  for (int rr = 0; rr < 4; ++rr) {
    float m = m_run[rr], ls = l_run[rr];
#pragma unroll
    for (int off = 1; off < 16; off <<= 1) {
      const float m2 = __shfl_xor(m, off);
      const float l2 = __shfl_xor(ls, off);
      const float nm = fmaxf(m, m2);
      ls = ls * __expf(m - nm) + l2 * __expf(m2 - nm);
      m = nm;
    }
    m_run[rr] = m;
    l_run[rr] = ls;   // raw sum for now
  }

  // cross-wt merge: wt=1 publishes, wt=0 merges + publishes final (m, inv_l)
  if (wt == 1 && l16 == 0) {
#pragma unroll
    for (int rr = 0; rr < 4; ++rr) {
      mlredA[wq][lg * 4 + rr][0] = m_run[rr];
      mlredA[wq][lg * 4 + rr][1] = l_run[rr];
    }
  }
  __syncthreads();
  if (wt == 0) {
#pragma unroll
    for (int rr = 0; rr < 4; ++rr) {
      const float m2 = mlredA[wq][lg * 4 + rr][0];
      const float l2 = mlredA[wq][lg * 4 + rr][1];
      const float nm = fmaxf(m_run[rr], m2);
      const float lf = l_run[rr] * __expf(m_run[rr] - nm) + l2 * __expf(m2 - nm);
      m_run[rr] = nm;
      l_run[rr] = 1.f / lf;
    }
    if (l16 == 0) {
#pragma unroll
      for (int rr = 0; rr < 4; ++rr) {
        mlredB[wq][lg * 4 + rr][0] = m_run[rr];
        mlredB[wq][lg * 4 + rr][1] = l_run[rr];
      }
    }
  }
  __syncthreads();
  if (wt == 1) {
#pragma unroll
    for (int rr = 0; rr < 4; ++rr) {
      m_run[rr] = mlredB[wq][lg * 4 + rr][0];
      l_run[rr] = mlredB[wq][lg * 4 + rr][1];
    }
  }

  // ---------------- pass 2: P write + P.V over this wave's t-half ---------
  f32x4 accC[4];
#pragma unroll
  for (int dt = 0; dt < 4; ++dt) accC[dt] = (f32x4){0.f, 0.f, 0.f, 0.f};

  float* arow = attn + ((size_t)(bh * SS + q0 + wq * 16)) * SS + tbase;

  for (int tt = 0; tt < 1024; tt += 64) {
    __syncthreads();
    {  // stage K
      const bf16* src = &kp[(size_t)(ks_wt * 1024 + tt + ks_r) * HD + ks_c];
      bf16* dst = &Ks[ks_wt][ks_r][ks_c];
      ((bf16x8*)dst)[0] = ((const bf16x8*)src)[0];
      ((bf16x8*)dst)[1] = ((const bf16x8*)src)[1];
    }
    {  // stage V transposed + swizzled: Vt[d][swz(t)] = V[t][d],
       // swz(t) = ((t>>3) ^ ((d>>3)&7))*8 + (t&7)
      const bf16* vsrc = &vp[(size_t)(vs_wt * 1024 + tt + vs_rc * 2) * HD + vs_dc * 8];
      const bf16x8 v0 = *(const bf16x8*)vsrc;
      const bf16x8 v1 = *(const bf16x8*)(vsrc + HD);
      const int colbase = (((vs_rc >> 2) ^ vs_dc) << 3) | ((vs_rc & 3) << 1);
#pragma unroll
      for (int j = 0; j < 8; ++j) {
        *(bf16x2*)&Vt[vs_wt][vs_dc * 8 + j][colbase] = (bf16x2){v0[j], v1[j]};
      }
    }
    __syncthreads();

    f32x4 accS[4];
#pragma unroll
    for (int n = 0; n < 4; ++n) {
      const bf16x8 kf0 = *(const bf16x8*)&Ks[wt][n * 16 + l16][lg * 8];
      const bf16x8 kf1 = *(const bf16x8*)&Ks[wt][n * 16 + l16][32 + lg * 8];
      f32x4 a = {0.f, 0.f, 0.f, 0.f};
      a = __builtin_amdgcn_mfma_f32_16x16x32_bf16(qf0, kf0, a, 0, 0, 0);
      a = __builtin_amdgcn_mfma_f32_16x16x32_bf16(qf1, kf1, a, 0, 0, 0);
      accS[n] = a;
    }

#pragma unroll
    for (int n = 0; n < 4; ++n) {
#pragma unroll
      for (int rr = 0; rr < 4; ++rr) {
        const int row = lg * 4 + rr;
        const float p = __expf(accS[n][rr] - m_run[rr]) * l_run[rr];
        arow[(size_t)row * SS + tt + n * 16 + l16] = p;
        Ps[w][row][n * 16 + l16] = (bf16)p;
      }
    }

#pragma unroll
    for (int ts = 0; ts < 2; ++ts) {
      const bf16x8 pa = *(const bf16x8*)&Ps[w][l16][ts * 32 + lg * 8];
#pragma unroll
      for (int dt = 0; dt < 4; ++dt) {
        const int vcol = (((ts * 4 + lg) ^ ((dt * 2 + (l16 >> 3)) & 7)) << 3);
        const bf16x8 vb = *(const bf16x8*)&Vt[wt][dt * 16 + l16][vcol];
        accC[dt] = __builtin_amdgcn_mfma_f32_16x16x32_bf16(pa, vb, accC[dt], 0, 0, 0);
      }
    }
  }

  // ---------------- ctx 2-way reduce across wt + write --------------------
  if (wt == 1) {
#pragma unroll
    for (int dt = 0; dt < 4; ++dt)
#pragma unroll
      for (int rr = 0; rr < 4; ++rr)
        ctxred[wq][lg * 4 + rr][dt * 16 + l16] = accC[dt][rr];
  }
  __syncthreads();
  if (wt == 0) {
    const int b = bh >> 3, h = bh & 7;
#pragma unroll
    for (int dt = 0; dt < 4; ++dt)
#pragma unroll
      for (int rr = 0; rr < 4; ++rr) {
        const float vsum = accC[dt][rr] + ctxred[wq][lg * 4 + rr][dt * 16 + l16];
        const int s = q0 + wq * 16 + lg * 4 + rr;
        ctx[((size_t)b * SS + s) * DIM + h * HD + dt * 16 + l16] = (bf16)vsum;
      }
  }
}

// ---------------------------------------------------------------------------
// K3: output projection, bf16 MFMA (R3-verified form). out = ctx @ Wo^T + bo.
// ---------------------------------------------------------------------------
__global__ __launch_bounds__(256) void out_proj_kernel(
    const bf16* __restrict__ ctx, const float* __restrict__ Wo, const float* __restrict__ bo,
    float* __restrict__ out)
{
  __shared__ bf16 As[128][72];
  __shared__ bf16 Bs[64][72];

  const int m0 = blockIdx.x * 128;
  const int n0 = blockIdx.y * 64;
  const int tid = threadIdx.x;
  const int w = tid >> 6, l = tid & 63;
  const int l16 = l & 15, lg = l >> 4;
  const int wm = w >> 1, wn = w & 1;

  f32x4 acc[4][2];
#pragma unroll
  for (int mf = 0; mf < 4; ++mf)
#pragma unroll
    for (int nf = 0; nf < 2; ++nf) acc[mf][nf] = (f32x4){0.f, 0.f, 0.f, 0.f};

  for (int k0 = 0; k0 < DIM; k0 += 64) {
    __syncthreads();
    {
      const int r = tid >> 1, hf = (tid & 1) * 32;
      const bf16* src = &ctx[(size_t)(m0 + r) * DIM + k0 + hf];
      bf16* dst = &As[r][hf];
#pragma unroll
      for (int i = 0; i < 4; ++i) ((bf16x8*)dst)[i] = ((const bf16x8*)src)[i];
    }
    if (tid < 128) {
      const int r = tid >> 1, hf = (tid & 1) * 32;
      const float* src = &Wo[(size_t)(n0 + r) * DIM + k0 + hf];
      bf16* dst = &Bs[r][hf];
#pragma unroll
      for (int i = 0; i < 4; ++i) ((bf16x8*)dst)[i] = cvt8(src + i * 8);
    }
    __syncthreads();

#pragma unroll
    for (int kk = 0; kk < 2; ++kk) {
      bf16x8 bfr[2];
      bfr[0] = *(const bf16x8*)&Bs[wn * 32 + l16][kk * 32 + lg * 8];
      bfr[1] = *(const bf16x8*)&Bs[wn * 32 + 16 + l16][kk * 32 + lg * 8];
#pragma unroll
      for (int mf = 0; mf < 4; ++mf) {
        const bf16x8 af = *(const bf16x8*)&As[wm * 64 + mf * 16 + l16][kk * 32 + lg * 8];
        acc[mf][0] = __builtin_amdgcn_mfma_f32_16x16x32_bf16(af, bfr[0], acc[mf][0], 0, 0, 0);
        acc[mf][1] = __builtin_amdgcn_mfma_f32_16x16x32_bf16(af, bfr[1], acc[mf][1], 0, 0, 0);
      }
    }
  }

#pragma unroll
  for (int mf = 0; mf < 4; ++mf) {
#pragma unroll
    for (int nf = 0; nf < 2; ++nf) {
      const int c = n0 + wn * 32 + nf * 16 + l16;
#pragma unroll
      for (int ri = 0; ri < 4; ++ri) {
        const int row = m0 + wm * 64 + mf * 16 + lg * 4 + ri;
        out[(size_t)row * DIM + c] = acc[mf][nf][ri] + bo[c];
      }
    }
  }
}

// ---------------------------------------------------------------------------
extern "C" void kernel_launch(void* const* d_in, const int* in_sizes, int n_in,
                              void* d_out, int out_size, void* d_ws, size_t ws_size,
                              hipStream_t stream) {
  const float* q  = (const float*)d_in[0];
  const float* k  = (const float*)d_in[1];
  const float* v  = (const float*)d_in[2];
  const float* Wq = (const float*)d_in[3];
  const float* bq = (const float*)d_in[4];
  const float* Wk = (const float*)d_in[5];
  const float* bk = (const float*)d_in[6];
  const float* Wv = (const float*)d_in[7];
  const float* bv = (const float*)d_in[8];
  const float* Wo = (const float*)d_in[9];
  const float* bo = (const float*)d_in[10];

  float* out0 = (float*)d_out;                     // [2,2048,512] fp32
  float* attn = out0 + (size_t)NB * SS * DIM;      // [2,8,2048,2048] fp32

  const size_t HSZ = (size_t)NB * NH * SS * HD;
  bf16* qh  = (bf16*)d_ws;
  bf16* kh  = qh + HSZ;
  bf16* vh  = kh + HSZ;
  bf16* ctx = vh + HSZ;                            // bf16 flat [B,S,DIM]

  dim3 g1(NB * SS / 128, DIM / 64, 3);
  qkv_proj_kernel<<<g1, 256, 0, stream>>>(q, k, v, Wq, bq, Wk, bk, Wv, bv, qh, kh, vh);

  dim3 g2(SS / 64, NB * NH);
  attn_kernel<<<g2, 512, 0, stream>>>(qh, kh, vh, attn, ctx);

  dim3 g3(NB * SS / 128, DIM / 64);
  out_proj_kernel<<<g3, 256, 0, stream>>>(ctx, Wo, bo, out0);
}